// Round 1
// baseline (1543.022 us; speedup 1.0000x reference)
//
#include <hip/hip_runtime.h>
#include <hip/hip_fp16.h>

typedef __attribute__((ext_vector_type(8))) short  s16x8;   // 8 bf16 (A/B frag, 4 VGPRs)
typedef __attribute__((ext_vector_type(4))) float  f32x4;   // MFMA C/D frag
typedef __attribute__((ext_vector_type(4))) unsigned short u16x4;
typedef unsigned short u16;

#define MFMA16(A, B, C) __builtin_amdgcn_mfma_f32_16x16x32_bf16((A), (B), (C), 0, 0, 0)

static __device__ __forceinline__ u16 f2bf(float f) {
    union { float f; unsigned u; } v; v.f = f;
    unsigned r = (v.u + 0x7fffu + ((v.u >> 16) & 1u)) >> 16;   // RNE
    return (u16)r;
}

static __device__ __forceinline__ s16x8 pack_bf16x8(float4 a, float4 b) {
    s16x8 r;
    r[0] = (short)f2bf(a.x); r[1] = (short)f2bf(a.y); r[2] = (short)f2bf(a.z); r[3] = (short)f2bf(a.w);
    r[4] = (short)f2bf(b.x); r[5] = (short)f2bf(b.y); r[6] = (short)f2bf(b.z); r[7] = (short)f2bf(b.w);
    return r;
}

static __device__ __forceinline__ float sigm(float x) {
    float e = __expf(-x);                 // x->-inf: e=inf -> 1/inf = 0  (no NaN)
    return 1.f / (1.f + e);
}
static __device__ __forceinline__ float tanh_s(float x) {
    x = fminf(fmaxf(x, -30.f), 30.f);     // avoid exp overflow -> NaN
    float e = __expf(-2.f * x);
    return (1.f - e) / (1.f + e);
}

// ---------------------------------------------------------------------------
// K1: x_gates[m=131072][512] (fp16) = x[m][300] @ W_ih^T + (b_ih + b_hh)
// bf16 MFMA, tiles BM=128 BN=128 BK=32 (K padded 300->320, zero-filled tail).
// grid (1024, 4), 256 threads (4 waves, 64x64 quadrant each).
// ---------------------------------------------------------------------------
__global__ __launch_bounds__(256, 2)
void k1_gemm_xgates(const float* __restrict__ x, const float* __restrict__ W_ih,
                    const float* __restrict__ b_ih, const float* __restrict__ b_hh,
                    __half* __restrict__ xg) {
    const int m0 = blockIdx.x * 128;
    const int n0 = blockIdx.y * 128;
    const int tid = threadIdx.x;
    const int wave = tid >> 6, lane = tid & 63;
    const int lanelo = lane & 15, quad = lane >> 4;
    const int mw = (wave & 1) * 64, nw = (wave >> 1) * 64;

    // LDS tiles, row stride padded 32->40 bf16 (80 B) to break bank alignment.
    __shared__ __align__(16) u16 As[128 * 40];
    __shared__ __align__(16) u16 Bs[128 * 40];

    f32x4 acc[4][4];
#pragma unroll
    for (int i = 0; i < 4; ++i)
#pragma unroll
        for (int j = 0; j < 4; ++j) acc[i][j] = (f32x4)0.f;

    const int srow = tid >> 1;           // 0..127
    const int scol = (tid & 1) * 16;     // 0 / 16

    for (int kc = 0; kc < 10; ++kc) {
        const int k0 = kc * 32;
        {   // stage A (x) fp32 -> bf16
            const float* src = x + (size_t)(m0 + srow) * 300 + k0 + scol;
#pragma unroll
            for (int i = 0; i < 4; ++i) {
                const int col = scol + i * 4;
                float4 v = {0.f, 0.f, 0.f, 0.f};
                if (k0 + col + 3 < 300) v = *(const float4*)(src + i * 4);
                u16x4 w; w.x = f2bf(v.x); w.y = f2bf(v.y); w.z = f2bf(v.z); w.w = f2bf(v.w);
                *(u16x4*)&As[srow * 40 + col] = w;
            }
            // stage B (W_ih)
            const float* srcB = W_ih + (size_t)(n0 + srow) * 300 + k0 + scol;
#pragma unroll
            for (int i = 0; i < 4; ++i) {
                const int col = scol + i * 4;
                float4 v = {0.f, 0.f, 0.f, 0.f};
                if (k0 + col + 3 < 300) v = *(const float4*)(srcB + i * 4);
                u16x4 w; w.x = f2bf(v.x); w.y = f2bf(v.y); w.z = f2bf(v.z); w.w = f2bf(v.w);
                *(u16x4*)&Bs[srow * 40 + col] = w;
            }
        }
        __syncthreads();

        s16x8 af[4], bf[4];
#pragma unroll
        for (int mt = 0; mt < 4; ++mt)
            af[mt] = *(const s16x8*)&As[(mw + mt * 16 + lanelo) * 40 + quad * 8];
#pragma unroll
        for (int nt = 0; nt < 4; ++nt)
            bf[nt] = *(const s16x8*)&Bs[(nw + nt * 16 + lanelo) * 40 + quad * 8];
#pragma unroll
        for (int mt = 0; mt < 4; ++mt)
#pragma unroll
            for (int nt = 0; nt < 4; ++nt)
                acc[mt][nt] = MFMA16(af[mt], bf[nt], acc[mt][nt]);
        __syncthreads();
    }

    // epilogue: C/D layout col=lane&15, row=(lane>>4)*4+reg
#pragma unroll
    for (int nt = 0; nt < 4; ++nt) {
        const int n = n0 + nw + nt * 16 + lanelo;
        const float bs = b_ih[n] + b_hh[n];
#pragma unroll
        for (int mt = 0; mt < 4; ++mt) {
            const int mr = m0 + mw + mt * 16 + quad * 4;
#pragma unroll
            for (int r = 0; r < 4; ++r)
                xg[(size_t)(mr + r) * 512 + n] = __float2half(acc[mt][nt][r] + bs);
        }
    }
}

// ---------------------------------------------------------------------------
// K2: LSTM recurrence. 128 WGs (one batch row each), 256 threads (4 waves).
// Per step: gates[512,16pad] = W_hh[512,128] (stationary bf16 A-frags in regs)
//           x h-replicated[128,16] (B-frags from 256 B of LDS), 32 MFMA/wave.
// Phase B (tid<128): + x_gates (fp16, depth-4 prefetch ring), activations,
// c/h update, h -> LDS (bf16) + h_seq (bf16, for K3).
// ---------------------------------------------------------------------------
__global__ __launch_bounds__(256, 1)
void k2_lstm_rec(const __half* __restrict__ xg_all, const float* __restrict__ W_hh,
                 u16* __restrict__ h_seq) {
    const int bb = blockIdx.x;           // batch row
    const int tid = threadIdx.x;
    const int wave = tid >> 6, lane = tid & 63;
    const int lanelo = lane & 15, quad = lane >> 4;
    const int kq8 = quad * 8;

    __shared__ __align__(16) u16  h_lds[128];      // bf16 h_{t-1}
    __shared__ __align__(16) float gates_lds[512]; // raw gate preacts (W_hh·h part)

    // --- load stationary W_hh A-fragments (bf16), 8 m-tiles x 4 k-chunks per wave
    s16x8 a_frag[8][4];
#pragma unroll
    for (int ti = 0; ti < 8; ++ti) {
        const int row = (wave * 8 + ti) * 16 + lanelo;      // gate row 0..511
#pragma unroll
        for (int kt = 0; kt < 4; ++kt) {
            const float* p = W_hh + (size_t)row * 128 + kt * 32 + kq8;
            float4 v0 = *(const float4*)p;
            float4 v1 = *(const float4*)(p + 4);
            a_frag[ti][kt] = pack_bf16x8(v0, v1);
        }
    }

    const __half* xg_b = xg_all + (size_t)bb * 1024 * 512;
    float c = 0.f;
    __half xg_pf[4][4];                  // prefetch ring [phase][gate-quarter]
    if (tid < 128) {
        h_lds[tid] = 0;
#pragma unroll
        for (int p = 0; p < 4; ++p)
#pragma unroll
            for (int q = 0; q < 4; ++q)
                xg_pf[p][q] = xg_b[(size_t)p * 512 + q * 128 + tid];
    }
    __syncthreads();

    for (int t = 0; t < 1024; t += 4) {
#pragma unroll
        for (int p = 0; p < 4; ++p) {
            const int tt = t + p;
            // ---- phase A: MFMA gates = W_hh · h  (h replicated across 16 cols)
            f32x4 acc[8];
#pragma unroll
            for (int ti = 0; ti < 8; ++ti) acc[ti] = (f32x4)0.f;
#pragma unroll
            for (int kt = 0; kt < 4; ++kt) {
                const s16x8 bfr = *(const s16x8*)&h_lds[kt * 32 + kq8];
#pragma unroll
                for (int ti = 0; ti < 8; ++ti)
                    acc[ti] = MFMA16(a_frag[ti][kt], bfr, acc[ti]);
            }
            // all 16 columns identical; lanes with (lane&15)==0 extract rows
            if (lanelo == 0) {
#pragma unroll
                for (int ti = 0; ti < 8; ++ti)
                    *reinterpret_cast<f32x4*>(&gates_lds[(wave * 8 + ti) * 16 + quad * 4]) = acc[ti];
            }
            __syncthreads();
            // ---- phase B: elementwise (128 threads)
            if (tid < 128) {
                float ig = gates_lds[tid]       + __half2float(xg_pf[p][0]);
                float fg = gates_lds[128 + tid] + __half2float(xg_pf[p][1]);
                float gg = gates_lds[256 + tid] + __half2float(xg_pf[p][2]);
                float og = gates_lds[384 + tid] + __half2float(xg_pf[p][3]);
                if (tt + 4 < 1024) {     // refill ring slot p for step tt+4
#pragma unroll
                    for (int q = 0; q < 4; ++q)
                        xg_pf[p][q] = xg_b[(size_t)(tt + 4) * 512 + q * 128 + tid];
                }
                ig = sigm(ig); fg = sigm(fg); gg = tanh_s(gg); og = sigm(og);
                c = fg * c + ig * gg;
                const float h = og * tanh_s(c);
                const u16 hb = f2bf(h);
                h_lds[tid] = hb;
                h_seq[((size_t)bb * 1024 + tt) * 128 + tid] = hb;
            }
            __syncthreads();
        }
    }
}

// ---------------------------------------------------------------------------
// K3: y[m=131072][64] = h_seq(bf16)[m][128] @ W1^T + b1   (fp32 out)
// grid 1024, 256 threads; K=128 in one shot; memory-bound.
// ---------------------------------------------------------------------------
__global__ __launch_bounds__(256, 2)
void k3_gemm_out(const u16* __restrict__ hseq, const float* __restrict__ W1,
                 const float* __restrict__ b1, float* __restrict__ y) {
    const int m0 = blockIdx.x * 128;
    const int tid = threadIdx.x;
    const int wave = tid >> 6, lane = tid & 63;
    const int lanelo = lane & 15, quad = lane >> 4;

    __shared__ __align__(16) u16 Ah[128 * 136];   // pad 128->136 (272 B rows)
    __shared__ __align__(16) u16 Bw[64 * 136];
    __shared__ float b1s[64];

    {   // stage A: h_seq bf16 straight copy
        const int row = tid >> 1, cg = (tid & 1) * 64;
        const u16* src = hseq + (size_t)(m0 + row) * 128 + cg;
#pragma unroll
        for (int i = 0; i < 8; ++i)
            *(s16x8*)&Ah[row * 136 + cg + i * 8] = *(const s16x8*)(src + i * 8);
    }
    {   // stage B: W1 fp32 -> bf16
        const int row = tid >> 2, cg = (tid & 3) * 32;
        const float* src = W1 + (size_t)row * 128 + cg;
#pragma unroll
        for (int i = 0; i < 4; ++i) {
            float4 v0 = *(const float4*)(src + i * 8);
            float4 v1 = *(const float4*)(src + i * 8 + 4);
            *(s16x8*)&Bw[row * 136 + cg + i * 8] = pack_bf16x8(v0, v1);
        }
    }
    if (tid < 64) b1s[tid] = b1[tid];
    __syncthreads();

    s16x8 af[2][4], bf[4][4];
#pragma unroll
    for (int mt = 0; mt < 2; ++mt)
#pragma unroll
        for (int kt = 0; kt < 4; ++kt)
            af[mt][kt] = *(const s16x8*)&Ah[(wave * 32 + mt * 16 + lanelo) * 136 + kt * 32 + quad * 8];
#pragma unroll
    for (int nt = 0; nt < 4; ++nt)
#pragma unroll
        for (int kt = 0; kt < 4; ++kt)
            bf[nt][kt] = *(const s16x8*)&Bw[(nt * 16 + lanelo) * 136 + kt * 32 + quad * 8];

    f32x4 acc[2][4];
#pragma unroll
    for (int mt = 0; mt < 2; ++mt)
#pragma unroll
        for (int nt = 0; nt < 4; ++nt) acc[mt][nt] = (f32x4)0.f;
#pragma unroll
    for (int kt = 0; kt < 4; ++kt)
#pragma unroll
        for (int mt = 0; mt < 2; ++mt)
#pragma unroll
            for (int nt = 0; nt < 4; ++nt)
                acc[mt][nt] = MFMA16(af[mt][kt], bf[nt][kt], acc[mt][nt]);

#pragma unroll
    for (int mt = 0; mt < 2; ++mt)
#pragma unroll
        for (int nt = 0; nt < 4; ++nt) {
            const int n = nt * 16 + lanelo;
            const float bs = b1s[n];
            const int mr = m0 + wave * 32 + mt * 16 + quad * 4;
#pragma unroll
            for (int r = 0; r < 4; ++r)
                y[(size_t)(mr + r) * 64 + n] = acc[mt][nt][r] + bs;
        }
}

// ---------------------------------------------------------------------------
extern "C" void kernel_launch(void* const* d_in, const int* in_sizes, int n_in,
                              void* d_out, int out_size, void* d_ws, size_t ws_size,
                              hipStream_t stream) {
    const float* x    = (const float*)d_in[0];
    const float* W_ih = (const float*)d_in[1];
    const float* W_hh = (const float*)d_in[2];
    const float* b_ih = (const float*)d_in[3];
    const float* b_hh = (const float*)d_in[4];
    const float* W1   = (const float*)d_in[5];
    const float* b1   = (const float*)d_in[6];
    float* y = (float*)d_out;

    const size_t XG_BYTES = (size_t)131072 * 512 * 2;   // x_gates fp16: 134 MB
    const size_t HS_BYTES = (size_t)131072 * 128 * 2;   // h_seq  bf16:  33.5 MB
    if (ws_size < XG_BYTES + HS_BYTES) return;          // sentinel: absmax == max|ref|

    __half* xg = (__half*)d_ws;
    u16* hseq  = (u16*)((char*)d_ws + XG_BYTES);

    k1_gemm_xgates<<<dim3(1024, 4), 256, 0, stream>>>(x, W_ih, b_ih, b_hh, xg);
    k2_lstm_rec<<<128, 256, 0, stream>>>(xg, W_hh, hseq);
    k3_gemm_out<<<1024, 256, 0, stream>>>(hseq, W1, b1, y);
}

// Round 2
// 1100.816 us; speedup vs baseline: 1.4017x; 1.4017x over previous
//
#include <hip/hip_runtime.h>
#include <hip/hip_fp16.h>

typedef __attribute__((ext_vector_type(8))) short  s16x8;   // 8 bf16 (A/B frag, 4 VGPRs)
typedef __attribute__((ext_vector_type(4))) float  f32x4;   // MFMA C/D frag
typedef __attribute__((ext_vector_type(4))) unsigned short u16x4;
typedef unsigned short u16;

#define MFMA16(A, B, C) __builtin_amdgcn_mfma_f32_16x16x32_bf16((A), (B), (C), 0, 0, 0)

static __device__ __forceinline__ u16 f2bf(float f) {
    union { float f; unsigned u; } v; v.f = f;
    unsigned r = (v.u + 0x7fffu + ((v.u >> 16) & 1u)) >> 16;   // RNE
    return (u16)r;
}

static __device__ __forceinline__ s16x8 pack_bf16x8(float4 a, float4 b) {
    s16x8 r;
    r[0] = (short)f2bf(a.x); r[1] = (short)f2bf(a.y); r[2] = (short)f2bf(a.z); r[3] = (short)f2bf(a.w);
    r[4] = (short)f2bf(b.x); r[5] = (short)f2bf(b.y); r[6] = (short)f2bf(b.z); r[7] = (short)f2bf(b.w);
    return r;
}

static __device__ __forceinline__ float hu2f(u16 v) {
    __half_raw hr; hr.x = v; return __half2float(__half(hr));
}

// fast sigmoid / tanh via v_exp + v_rcp (saturating, NaN-free at extremes)
static __device__ __forceinline__ float sigm(float x) {
    return __builtin_amdgcn_rcpf(1.f + __expf(-x));
}
static __device__ __forceinline__ float tanh_f(float x) {
    float e = __expf(-2.f * x);          // x->-inf: e=inf -> rcp=0 -> -1; x->+inf: e=0 -> +1
    return fmaf(2.f, __builtin_amdgcn_rcpf(1.f + e), -1.f);
}

// ---------------------------------------------------------------------------
// K1: x_gates[m=131072][512] (fp16) = x[m][300] @ W_ih^T + (b_ih + b_hh)
// (unchanged from round 1)
// ---------------------------------------------------------------------------
__global__ __launch_bounds__(256, 2)
void k1_gemm_xgates(const float* __restrict__ x, const float* __restrict__ W_ih,
                    const float* __restrict__ b_ih, const float* __restrict__ b_hh,
                    __half* __restrict__ xg) {
    const int m0 = blockIdx.x * 128;
    const int n0 = blockIdx.y * 128;
    const int tid = threadIdx.x;
    const int wave = tid >> 6, lane = tid & 63;
    const int lanelo = lane & 15, quad = lane >> 4;
    const int mw = (wave & 1) * 64, nw = (wave >> 1) * 64;

    __shared__ __align__(16) u16 As[128 * 40];
    __shared__ __align__(16) u16 Bs[128 * 40];

    f32x4 acc[4][4];
#pragma unroll
    for (int i = 0; i < 4; ++i)
#pragma unroll
        for (int j = 0; j < 4; ++j) acc[i][j] = (f32x4)0.f;

    const int srow = tid >> 1;
    const int scol = (tid & 1) * 16;

    for (int kc = 0; kc < 10; ++kc) {
        const int k0 = kc * 32;
        {
            const float* src = x + (size_t)(m0 + srow) * 300 + k0 + scol;
#pragma unroll
            for (int i = 0; i < 4; ++i) {
                const int col = scol + i * 4;
                float4 v = {0.f, 0.f, 0.f, 0.f};
                if (k0 + col + 3 < 300) v = *(const float4*)(src + i * 4);
                u16x4 w; w.x = f2bf(v.x); w.y = f2bf(v.y); w.z = f2bf(v.z); w.w = f2bf(v.w);
                *(u16x4*)&As[srow * 40 + col] = w;
            }
            const float* srcB = W_ih + (size_t)(n0 + srow) * 300 + k0 + scol;
#pragma unroll
            for (int i = 0; i < 4; ++i) {
                const int col = scol + i * 4;
                float4 v = {0.f, 0.f, 0.f, 0.f};
                if (k0 + col + 3 < 300) v = *(const float4*)(srcB + i * 4);
                u16x4 w; w.x = f2bf(v.x); w.y = f2bf(v.y); w.z = f2bf(v.z); w.w = f2bf(v.w);
                *(u16x4*)&Bs[srow * 40 + col] = w;
            }
        }
        __syncthreads();

        s16x8 af[4], bf[4];
#pragma unroll
        for (int mt = 0; mt < 4; ++mt)
            af[mt] = *(const s16x8*)&As[(mw + mt * 16 + lanelo) * 40 + quad * 8];
#pragma unroll
        for (int nt = 0; nt < 4; ++nt)
            bf[nt] = *(const s16x8*)&Bs[(nw + nt * 16 + lanelo) * 40 + quad * 8];
#pragma unroll
        for (int mt = 0; mt < 4; ++mt)
#pragma unroll
            for (int nt = 0; nt < 4; ++nt)
                acc[mt][nt] = MFMA16(af[mt], bf[nt], acc[mt][nt]);
        __syncthreads();
    }

#pragma unroll
    for (int nt = 0; nt < 4; ++nt) {
        const int n = n0 + nw + nt * 16 + lanelo;
        const float bs = b_ih[n] + b_hh[n];
#pragma unroll
        for (int mt = 0; mt < 4; ++mt) {
            const int mr = m0 + mw + mt * 16 + quad * 4;
#pragma unroll
            for (int r = 0; r < 4; ++r)
                xg[(size_t)(mr + r) * 512 + n] = __float2half(acc[mt][nt][r] + bs);
        }
    }
}

// ---------------------------------------------------------------------------
// K2 v2: LSTM recurrence. 64 WGs, each handles TWO batch rows; 256 threads.
//
// MFMA: gates[512, 2b] = W_hh[512,128] (stationary bf16 A-frags) x h[128, 2b]
// (B cols 0-7 = batch0, 8-15 = batch1). Wave w's 8 tiles are remapped so it
// computes ALL FOUR gates for h-indices [32w, 32w+32): tile ti -> gate g=ti>>1,
// rows g*128 + 32w + (ti&1)*16 + [0,16).
//
// Elementwise: the 64 lanes of a wave map bijectively to (batch, h-index):
// b = lanelo>>3, jl = ((lanelo>>2)&1)*16 + quad*4 + (lanelo&3). Each lane
// extracts its 4 gate values from its OWN acc regs via a 7-cndmask select
// tree -> one full LSTM cell update per lane, no gates-LDS round trip.
//
// I/O: xg staged to LDS 8 steps/chunk (global->regs at chunk start, regs->LDS
// at chunk end); h_seq buffered in LDS, flushed once per chunk. Per-step
// barrier (1!) drains only lgkmcnt. h double-buffered by step parity.
// ---------------------------------------------------------------------------
__global__ __launch_bounds__(256, 1)
void k2_lstm_rec(const __half* __restrict__ xg_all, const float* __restrict__ W_hh,
                 u16* __restrict__ h_seq) {
    const int bb = blockIdx.x;            // batch PAIR index, 0..63
    const int tid = threadIdx.x;
    const int wave = tid >> 6, lane = tid & 63;
    const int lanelo = lane & 15, quad = lane >> 4;
    const int kq8 = quad * 8;

    const int b_sel = lanelo >> 3;              // batch within pair
    const int s_sel = (lanelo >> 2) & 1;
    const int r_sel = lanelo & 3;
    const int hj = wave * 32 + s_sel * 16 + quad * 4 + r_sel;   // 0..127

    __shared__ __align__(16) u16 h_lds[2][2][128];    // [parity][batch][H]
    __shared__ __align__(16) u16 xg_lds[8][2][512];   // [step][batch][4H], fp16 bits
    __shared__ __align__(16) u16 h_hist[8][2][128];   // chunk output buffer

    // --- stationary W_hh A-fragments (bf16): 8 tiles x 4 k-chunks per wave
    s16x8 a_frag[8][4];
#pragma unroll
    for (int ti = 0; ti < 8; ++ti) {
        const int g = ti >> 1, s = ti & 1;
        const int row = g * 128 + wave * 32 + s * 16 + lanelo;
#pragma unroll
        for (int kt = 0; kt < 4; ++kt) {
            const float* p = W_hh + (size_t)row * 128 + kt * 32 + kq8;
            float4 v0 = *(const float4*)p;
            float4 v1 = *(const float4*)(p + 4);
            a_frag[ti][kt] = pack_bf16x8(v0, v1);
        }
    }

    // --- xg chunk staging map: 256 threads x 64 B cover 8 steps x 2 batches x 512
    const int bS = tid >> 7;              // staging batch
    const int r7 = tid & 127;
    const int pS = r7 >> 4;               // step within chunk
    const int cS = (r7 & 15) * 32;        // column (halves)
    const u16* xsrc = (const u16*)xg_all + ((size_t)(bb * 2 + bS) * 1024 + pS) * 512 + cS;

    // prime chunk 0
    s16x8 xr[4];
#pragma unroll
    for (int i = 0; i < 4; ++i) xr[i] = *(const s16x8*)(xsrc + i * 8);
    ((unsigned*)h_lds)[tid] = 0;          // zero both parities of h
    float c = 0.f;
#pragma unroll
    for (int i = 0; i < 4; ++i) *(s16x8*)&xg_lds[pS][bS][cS + i * 8] = xr[i];
    __syncthreads();

    for (int t0 = 0; t0 < 1024; t0 += 8) {
        const bool have_next = (t0 + 8) < 1024;
        if (have_next) {
            const u16* s = xsrc + (size_t)(t0 + 8) * 512;
#pragma unroll
            for (int i = 0; i < 4; ++i) xr[i] = *(const s16x8*)(s + i * 8);
        }
#pragma unroll
        for (int p = 0; p < 8; ++p) {
            const int par = p & 1;        // t0 is a multiple of 8
            // issue xg + h reads first; latency hides behind MFMA
            float xgv[4];
#pragma unroll
            for (int g = 0; g < 4; ++g)
                xgv[g] = hu2f(xg_lds[p][b_sel][g * 128 + hj]);
            s16x8 bfr[4];
#pragma unroll
            for (int kt = 0; kt < 4; ++kt)
                bfr[kt] = *(const s16x8*)&h_lds[par][b_sel][kt * 32 + kq8];

            f32x4 acc[8];
#pragma unroll
            for (int ti = 0; ti < 8; ++ti) acc[ti] = (f32x4)0.f;
#pragma unroll
            for (int kt = 0; kt < 4; ++kt)
#pragma unroll
                for (int ti = 0; ti < 8; ++ti)
                    acc[ti] = MFMA16(a_frag[ti][kt], bfr[kt], acc[ti]);

            // per-lane gate extraction: acc[g*2+s_sel][r_sel]
            const bool r1 = (lanelo & 1) != 0;
            const bool r2 = (lanelo & 2) != 0;
            const bool sS = (lanelo & 4) != 0;
            float gv[4];
#pragma unroll
            for (int g = 0; g < 4; ++g) {
                const f32x4 e0 = acc[g * 2], e1 = acc[g * 2 + 1];
                float x0 = r1 ? e0[1] : e0[0];
                float x1 = r1 ? e0[3] : e0[2];
                float x2 = r1 ? e1[1] : e1[0];
                float x3 = r1 ? e1[3] : e1[2];
                float y0 = r2 ? x1 : x0;
                float y1 = r2 ? x3 : x2;
                gv[g] = (sS ? y1 : y0) + xgv[g];
            }
            const float ig = sigm(gv[0]);
            const float fg = sigm(gv[1]);
            const float gg = tanh_f(gv[2]);
            const float og = sigm(gv[3]);
            c = fmaf(fg, c, ig * gg);
            const float h = og * tanh_f(c);
            const u16 hb = f2bf(h);
            h_lds[par ^ 1][b_sel][hj] = hb;
            h_hist[p][b_sel][hj] = hb;
            __syncthreads();
        }
        {   // flush h_hist -> h_seq (one coalesced 16B store per thread)
            const int p2 = tid >> 5, rem = tid & 31, b2 = rem >> 4, j0 = (rem & 15) * 8;
            s16x8 hv = *(const s16x8*)&h_hist[p2][b2][j0];
            *(s16x8*)(h_seq + ((size_t)(bb * 2 + b2) * 1024 + t0 + p2) * 128 + j0) = hv;
        }
        if (have_next) {
#pragma unroll
            for (int i = 0; i < 4; ++i) *(s16x8*)&xg_lds[pS][bS][cS + i * 8] = xr[i];
        }
        __syncthreads();
    }
}

// ---------------------------------------------------------------------------
// K3: y[m=131072][64] = h_seq(bf16)[m][128] @ W1^T + b1   (unchanged)
// ---------------------------------------------------------------------------
__global__ __launch_bounds__(256, 2)
void k3_gemm_out(const u16* __restrict__ hseq, const float* __restrict__ W1,
                 const float* __restrict__ b1, float* __restrict__ y) {
    const int m0 = blockIdx.x * 128;
    const int tid = threadIdx.x;
    const int wave = tid >> 6, lane = tid & 63;
    const int lanelo = lane & 15, quad = lane >> 4;

    __shared__ __align__(16) u16 Ah[128 * 136];
    __shared__ __align__(16) u16 Bw[64 * 136];
    __shared__ float b1s[64];

    {
        const int row = tid >> 1, cg = (tid & 1) * 64;
        const u16* src = hseq + (size_t)(m0 + row) * 128 + cg;
#pragma unroll
        for (int i = 0; i < 8; ++i)
            *(s16x8*)&Ah[row * 136 + cg + i * 8] = *(const s16x8*)(src + i * 8);
    }
    {
        const int row = tid >> 2, cg = (tid & 3) * 32;
        const float* src = W1 + (size_t)row * 128 + cg;
#pragma unroll
        for (int i = 0; i < 4; ++i) {
            float4 v0 = *(const float4*)(src + i * 8);
            float4 v1 = *(const float4*)(src + i * 8 + 4);
            *(s16x8*)&Bw[row * 136 + cg + i * 8] = pack_bf16x8(v0, v1);
        }
    }
    if (tid < 64) b1s[tid] = b1[tid];
    __syncthreads();

    s16x8 af[2][4], bf[4][4];
#pragma unroll
    for (int mt = 0; mt < 2; ++mt)
#pragma unroll
        for (int kt = 0; kt < 4; ++kt)
            af[mt][kt] = *(const s16x8*)&Ah[(wave * 32 + mt * 16 + lanelo) * 136 + kt * 32 + quad * 8];
#pragma unroll
    for (int nt = 0; nt < 4; ++nt)
#pragma unroll
        for (int kt = 0; kt < 4; ++kt)
            bf[nt][kt] = *(const s16x8*)&Bw[(nt * 16 + lanelo) * 136 + kt * 32 + quad * 8];

    f32x4 acc[2][4];
#pragma unroll
    for (int mt = 0; mt < 2; ++mt)
#pragma unroll
        for (int nt = 0; nt < 4; ++nt) acc[mt][nt] = (f32x4)0.f;
#pragma unroll
    for (int kt = 0; kt < 4; ++kt)
#pragma unroll
        for (int mt = 0; mt < 2; ++mt)
#pragma unroll
            for (int nt = 0; nt < 4; ++nt)
                acc[mt][nt] = MFMA16(af[mt][kt], bf[nt][kt], acc[mt][nt]);

#pragma unroll
    for (int mt = 0; mt < 2; ++mt)
#pragma unroll
        for (int nt = 0; nt < 4; ++nt) {
            const int n = nt * 16 + lanelo;
            const float bs = b1s[n];
            const int mr = m0 + wave * 32 + mt * 16 + quad * 4;
#pragma unroll
            for (int r = 0; r < 4; ++r)
                y[(size_t)(mr + r) * 64 + n] = acc[mt][nt][r] + bs;
        }
}

// ---------------------------------------------------------------------------
extern "C" void kernel_launch(void* const* d_in, const int* in_sizes, int n_in,
                              void* d_out, int out_size, void* d_ws, size_t ws_size,
                              hipStream_t stream) {
    const float* x    = (const float*)d_in[0];
    const float* W_ih = (const float*)d_in[1];
    const float* W_hh = (const float*)d_in[2];
    const float* b_ih = (const float*)d_in[3];
    const float* b_hh = (const float*)d_in[4];
    const float* W1   = (const float*)d_in[5];
    const float* b1   = (const float*)d_in[6];
    float* y = (float*)d_out;

    const size_t XG_BYTES = (size_t)131072 * 512 * 2;   // x_gates fp16: 134 MB
    const size_t HS_BYTES = (size_t)131072 * 128 * 2;   // h_seq  bf16:  33.5 MB
    if (ws_size < XG_BYTES + HS_BYTES) return;

    __half* xg = (__half*)d_ws;
    u16* hseq  = (u16*)((char*)d_ws + XG_BYTES);

    k1_gemm_xgates<<<dim3(1024, 4), 256, 0, stream>>>(x, W_ih, b_ih, b_hh, xg);
    k2_lstm_rec<<<64, 256, 0, stream>>>(xg, W_hh, hseq);
    k3_gemm_out<<<1024, 256, 0, stream>>>(hseq, W1, b1, y);
}

// Round 3
// 1098.047 us; speedup vs baseline: 1.4052x; 1.0025x over previous
//
#include <hip/hip_runtime.h>
#include <hip/hip_fp16.h>

typedef __attribute__((ext_vector_type(8))) short  s16x8;   // 8 bf16 (A/B frag, 4 VGPRs)
typedef __attribute__((ext_vector_type(4))) float  f32x4;   // MFMA C/D frag
typedef __attribute__((ext_vector_type(4))) unsigned short u16x4;
typedef unsigned short u16;

#define MFMA16(A, B, C) __builtin_amdgcn_mfma_f32_16x16x32_bf16((A), (B), (C), 0, 0, 0)

static __device__ __forceinline__ u16 f2bf(float f) {
    union { float f; unsigned u; } v; v.f = f;
    unsigned r = (v.u + 0x7fffu + ((v.u >> 16) & 1u)) >> 16;   // RNE
    return (u16)r;
}

static __device__ __forceinline__ s16x8 pack_bf16x8(float4 a, float4 b) {
    s16x8 r;
    r[0] = (short)f2bf(a.x); r[1] = (short)f2bf(a.y); r[2] = (short)f2bf(a.z); r[3] = (short)f2bf(a.w);
    r[4] = (short)f2bf(b.x); r[5] = (short)f2bf(b.y); r[6] = (short)f2bf(b.z); r[7] = (short)f2bf(b.w);
    return r;
}

static __device__ __forceinline__ float hu2f(u16 v) {
    __half_raw hr; hr.x = v; return __half2float(__half(hr));
}

// fast sigmoid / tanh via v_exp + v_rcp (saturating, NaN-free at extremes)
static __device__ __forceinline__ float sigm(float x) {
    return __builtin_amdgcn_rcpf(1.f + __expf(-x));
}
static __device__ __forceinline__ float tanh_f(float x) {
    float e = __expf(-2.f * x);          // x->-inf: e=inf -> rcp=0 -> -1; x->+inf: e=0 -> +1
    return fmaf(2.f, __builtin_amdgcn_rcpf(1.f + e), -1.f);
}

// LDS-only workgroup barrier: drains lgkmcnt (LDS ordering) but deliberately
// does NOT drain vmcnt -- global loads/stores stay in flight across it.
// All cross-wave communication in k2 goes through LDS, so this is sufficient.
static __device__ __forceinline__ void wg_barrier() {
    asm volatile("s_waitcnt lgkmcnt(0)\n\ts_barrier" ::: "memory");
}

// ---------------------------------------------------------------------------
// K1: x_gates[m=131072][512] (fp16) = x[m][300] @ W_ih^T + (b_ih + b_hh)
// (unchanged)
// ---------------------------------------------------------------------------
__global__ __launch_bounds__(256, 2)
void k1_gemm_xgates(const float* __restrict__ x, const float* __restrict__ W_ih,
                    const float* __restrict__ b_ih, const float* __restrict__ b_hh,
                    __half* __restrict__ xg) {
    const int m0 = blockIdx.x * 128;
    const int n0 = blockIdx.y * 128;
    const int tid = threadIdx.x;
    const int wave = tid >> 6, lane = tid & 63;
    const int lanelo = lane & 15, quad = lane >> 4;
    const int mw = (wave & 1) * 64, nw = (wave >> 1) * 64;

    __shared__ __align__(16) u16 As[128 * 40];
    __shared__ __align__(16) u16 Bs[128 * 40];

    f32x4 acc[4][4];
#pragma unroll
    for (int i = 0; i < 4; ++i)
#pragma unroll
        for (int j = 0; j < 4; ++j) acc[i][j] = (f32x4)0.f;

    const int srow = tid >> 1;
    const int scol = (tid & 1) * 16;

    for (int kc = 0; kc < 10; ++kc) {
        const int k0 = kc * 32;
        {
            const float* src = x + (size_t)(m0 + srow) * 300 + k0 + scol;
#pragma unroll
            for (int i = 0; i < 4; ++i) {
                const int col = scol + i * 4;
                float4 v = {0.f, 0.f, 0.f, 0.f};
                if (k0 + col + 3 < 300) v = *(const float4*)(src + i * 4);
                u16x4 w; w.x = f2bf(v.x); w.y = f2bf(v.y); w.z = f2bf(v.z); w.w = f2bf(v.w);
                *(u16x4*)&As[srow * 40 + col] = w;
            }
            const float* srcB = W_ih + (size_t)(n0 + srow) * 300 + k0 + scol;
#pragma unroll
            for (int i = 0; i < 4; ++i) {
                const int col = scol + i * 4;
                float4 v = {0.f, 0.f, 0.f, 0.f};
                if (k0 + col + 3 < 300) v = *(const float4*)(srcB + i * 4);
                u16x4 w; w.x = f2bf(v.x); w.y = f2bf(v.y); w.z = f2bf(v.z); w.w = f2bf(v.w);
                *(u16x4*)&Bs[srow * 40 + col] = w;
            }
        }
        __syncthreads();

        s16x8 af[4], bf[4];
#pragma unroll
        for (int mt = 0; mt < 4; ++mt)
            af[mt] = *(const s16x8*)&As[(mw + mt * 16 + lanelo) * 40 + quad * 8];
#pragma unroll
        for (int nt = 0; nt < 4; ++nt)
            bf[nt] = *(const s16x8*)&Bs[(nw + nt * 16 + lanelo) * 40 + quad * 8];
#pragma unroll
        for (int mt = 0; mt < 4; ++mt)
#pragma unroll
            for (int nt = 0; nt < 4; ++nt)
                acc[mt][nt] = MFMA16(af[mt], bf[nt], acc[mt][nt]);
        __syncthreads();
    }

#pragma unroll
    for (int nt = 0; nt < 4; ++nt) {
        const int n = n0 + nw + nt * 16 + lanelo;
        const float bs = b_ih[n] + b_hh[n];
#pragma unroll
        for (int mt = 0; mt < 4; ++mt) {
            const int mr = m0 + mw + mt * 16 + quad * 4;
#pragma unroll
            for (int r = 0; r < 4; ++r)
                xg[(size_t)(mr + r) * 512 + n] = __float2half(acc[mt][nt][r] + bs);
        }
    }
}

// ---------------------------------------------------------------------------
// K2 v3: LSTM recurrence, 64 WGs x 2 batch rows, 256 threads.
// Same MFMA/lane-bijection structure as v2. New in v3:
//  - ALL barriers are bare s_barrier + lgkmcnt(0) (wg_barrier): vmcnt is never
//    drained at a barrier, so the chunk-prefetch global loads and per-step
//    h_seq stores stay in flight across steps.
//  - h_seq written directly per step by the owning lane (no h_hist buffer).
// ---------------------------------------------------------------------------
__global__ __launch_bounds__(256, 1)
void k2_lstm_rec(const __half* __restrict__ xg_all, const float* __restrict__ W_hh,
                 u16* __restrict__ h_seq) {
    const int bb = blockIdx.x;            // batch PAIR index, 0..63
    const int tid = threadIdx.x;
    const int wave = tid >> 6, lane = tid & 63;
    const int lanelo = lane & 15, quad = lane >> 4;
    const int kq8 = quad * 8;

    const int b_sel = lanelo >> 3;              // batch within pair
    const int s_sel = (lanelo >> 2) & 1;
    const int r_sel = lanelo & 3;
    const int hj = wave * 32 + s_sel * 16 + quad * 4 + r_sel;   // 0..127

    __shared__ __align__(16) u16 h_lds[2][2][128];    // [parity][batch][H]
    __shared__ __align__(16) u16 xg_lds[8][2][512];   // [step][batch][4H], fp16 bits

    // --- stationary W_hh A-fragments (bf16): 8 tiles x 4 k-chunks per wave
    s16x8 a_frag[8][4];
#pragma unroll
    for (int ti = 0; ti < 8; ++ti) {
        const int g = ti >> 1, s = ti & 1;
        const int row = g * 128 + wave * 32 + s * 16 + lanelo;
#pragma unroll
        for (int kt = 0; kt < 4; ++kt) {
            const float* p = W_hh + (size_t)row * 128 + kt * 32 + kq8;
            float4 v0 = *(const float4*)p;
            float4 v1 = *(const float4*)(p + 4);
            a_frag[ti][kt] = pack_bf16x8(v0, v1);
        }
    }

    // --- xg chunk staging map: 256 threads x 64 B cover 8 steps x 2 batches x 512
    const int bS = tid >> 7;              // staging batch
    const int r7 = tid & 127;
    const int pS = r7 >> 4;               // step within chunk
    const int cS = (r7 & 15) * 32;        // column (halves)
    const u16* xsrc = (const u16*)xg_all + ((size_t)(bb * 2 + bS) * 1024 + pS) * 512 + cS;

    // prime chunk 0
    s16x8 xr[4];
#pragma unroll
    for (int i = 0; i < 4; ++i) xr[i] = *(const s16x8*)(xsrc + i * 8);
    ((unsigned*)h_lds)[tid] = 0;          // zero both parities of h
    float c = 0.f;
#pragma unroll
    for (int i = 0; i < 4; ++i) *(s16x8*)&xg_lds[pS][bS][cS + i * 8] = xr[i];
    __syncthreads();                      // once, outside the hot loop

    u16* hout = h_seq + (size_t)(bb * 2 + b_sel) * 1024 * 128 + hj;

    for (int t0 = 0; t0 < 1024; t0 += 8) {
        const bool have_next = (t0 + 8) < 1024;
        if (have_next) {                  // prefetch next chunk into registers;
            const u16* s = xsrc + (size_t)(t0 + 8) * 512;   // no barrier drains it
#pragma unroll
            for (int i = 0; i < 4; ++i) xr[i] = *(const s16x8*)(s + i * 8);
        }
#pragma unroll
        for (int p = 0; p < 8; ++p) {
            const int par = p & 1;
            // issue LDS reads first; latency hides behind MFMA
            float xgv[4];
#pragma unroll
            for (int g = 0; g < 4; ++g)
                xgv[g] = hu2f(xg_lds[p][b_sel][g * 128 + hj]);
            s16x8 bfr[4];
#pragma unroll
            for (int kt = 0; kt < 4; ++kt)
                bfr[kt] = *(const s16x8*)&h_lds[par][b_sel][kt * 32 + kq8];

            f32x4 acc[8];
#pragma unroll
            for (int ti = 0; ti < 8; ++ti) acc[ti] = (f32x4)0.f;
#pragma unroll
            for (int kt = 0; kt < 4; ++kt)
#pragma unroll
                for (int ti = 0; ti < 8; ++ti)
                    acc[ti] = MFMA16(a_frag[ti][kt], bfr[kt], acc[ti]);

            // per-lane gate extraction: acc[g*2+s_sel][r_sel] (dynamic reg index
            // lowered as a cndmask select tree)
            const bool r1 = (lanelo & 1) != 0;
            const bool r2 = (lanelo & 2) != 0;
            const bool sS = (lanelo & 4) != 0;
            float gv[4];
#pragma unroll
            for (int g = 0; g < 4; ++g) {
                const f32x4 e0 = acc[g * 2], e1 = acc[g * 2 + 1];
                float x0 = r1 ? e0[1] : e0[0];
                float x1 = r1 ? e0[3] : e0[2];
                float x2 = r1 ? e1[1] : e1[0];
                float x3 = r1 ? e1[3] : e1[2];
                float y0 = r2 ? x1 : x0;
                float y1 = r2 ? x3 : x2;
                gv[g] = (sS ? y1 : y0) + xgv[g];
            }
            const float ig = sigm(gv[0]);
            const float fg = sigm(gv[1]);
            const float gg = tanh_f(gv[2]);
            const float og = sigm(gv[3]);
            c = fmaf(fg, c, ig * gg);
            const float h = og * tanh_f(c);
            const u16 hb = f2bf(h);
            h_lds[par ^ 1][b_sel][hj] = hb;
            hout[(size_t)(t0 + p) * 128] = hb;   // store floats; never drained
            wg_barrier();
        }
        if (have_next) {   // xr -> LDS; compiler waits vmcnt for xr (8 steps old)
#pragma unroll
            for (int i = 0; i < 4; ++i) *(s16x8*)&xg_lds[pS][bS][cS + i * 8] = xr[i];
            wg_barrier();
        }
    }
}

// ---------------------------------------------------------------------------
// K3: y[m=131072][64] = h_seq(bf16)[m][128] @ W1^T + b1   (unchanged)
// ---------------------------------------------------------------------------
__global__ __launch_bounds__(256, 2)
void k3_gemm_out(const u16* __restrict__ hseq, const float* __restrict__ W1,
                 const float* __restrict__ b1, float* __restrict__ y) {
    const int m0 = blockIdx.x * 128;
    const int tid = threadIdx.x;
    const int wave = tid >> 6, lane = tid & 63;
    const int lanelo = lane & 15, quad = lane >> 4;

    __shared__ __align__(16) u16 Ah[128 * 136];
    __shared__ __align__(16) u16 Bw[64 * 136];
    __shared__ float b1s[64];

    {
        const int row = tid >> 1, cg = (tid & 1) * 64;
        const u16* src = hseq + (size_t)(m0 + row) * 128 + cg;
#pragma unroll
        for (int i = 0; i < 8; ++i)
            *(s16x8*)&Ah[row * 136 + cg + i * 8] = *(const s16x8*)(src + i * 8);
    }
    {
        const int row = tid >> 2, cg = (tid & 3) * 32;
        const float* src = W1 + (size_t)row * 128 + cg;
#pragma unroll
        for (int i = 0; i < 4; ++i) {
            float4 v0 = *(const float4*)(src + i * 8);
            float4 v1 = *(const float4*)(src + i * 8 + 4);
            *(s16x8*)&Bw[row * 136 + cg + i * 8] = pack_bf16x8(v0, v1);
        }
    }
    if (tid < 64) b1s[tid] = b1[tid];
    __syncthreads();

    s16x8 af[2][4], bf[4][4];
#pragma unroll
    for (int mt = 0; mt < 2; ++mt)
#pragma unroll
        for (int kt = 0; kt < 4; ++kt)
            af[mt][kt] = *(const s16x8*)&Ah[(wave * 32 + mt * 16 + lanelo) * 136 + kt * 32 + quad * 8];
#pragma unroll
    for (int nt = 0; nt < 4; ++nt)
#pragma unroll
        for (int kt = 0; kt < 4; ++kt)
            bf[nt][kt] = *(const s16x8*)&Bw[(nt * 16 + lanelo) * 136 + kt * 32 + quad * 8];

    f32x4 acc[2][4];
#pragma unroll
    for (int mt = 0; mt < 2; ++mt)
#pragma unroll
        for (int nt = 0; nt < 4; ++nt) acc[mt][nt] = (f32x4)0.f;
#pragma unroll
    for (int kt = 0; kt < 4; ++kt)
#pragma unroll
        for (int mt = 0; mt < 2; ++mt)
#pragma unroll
            for (int nt = 0; nt < 4; ++nt)
                acc[mt][nt] = MFMA16(af[mt][kt], bf[nt][kt], acc[mt][nt]);

#pragma unroll
    for (int mt = 0; mt < 2; ++mt)
#pragma unroll
        for (int nt = 0; nt < 4; ++nt) {
            const int n = nt * 16 + lanelo;
            const float bs = b1s[n];
            const int mr = m0 + wave * 32 + mt * 16 + quad * 4;
#pragma unroll
            for (int r = 0; r < 4; ++r)
                y[(size_t)(mr + r) * 64 + n] = acc[mt][nt][r] + bs;
        }
}

// ---------------------------------------------------------------------------
extern "C" void kernel_launch(void* const* d_in, const int* in_sizes, int n_in,
                              void* d_out, int out_size, void* d_ws, size_t ws_size,
                              hipStream_t stream) {
    const float* x    = (const float*)d_in[0];
    const float* W_ih = (const float*)d_in[1];
    const float* W_hh = (const float*)d_in[2];
    const float* b_ih = (const float*)d_in[3];
    const float* b_hh = (const float*)d_in[4];
    const float* W1   = (const float*)d_in[5];
    const float* b1   = (const float*)d_in[6];
    float* y = (float*)d_out;

    const size_t XG_BYTES = (size_t)131072 * 512 * 2;   // x_gates fp16: 134 MB
    const size_t HS_BYTES = (size_t)131072 * 128 * 2;   // h_seq  bf16:  33.5 MB
    if (ws_size < XG_BYTES + HS_BYTES) return;

    __half* xg = (__half*)d_ws;
    u16* hseq  = (u16*)((char*)d_ws + XG_BYTES);

    k1_gemm_xgates<<<dim3(1024, 4), 256, 0, stream>>>(x, W_ih, b_ih, b_hh, xg);
    k2_lstm_rec<<<64, 256, 0, stream>>>(xg, W_hh, hseq);
    k3_gemm_out<<<1024, 256, 0, stream>>>(hseq, W1, b1, y);
}

// Round 4
// 978.085 us; speedup vs baseline: 1.5776x; 1.1226x over previous
//
#include <hip/hip_runtime.h>
#include <hip/hip_fp16.h>

typedef __attribute__((ext_vector_type(8))) short  s16x8;   // 8x16-bit (4 VGPRs)
typedef __attribute__((ext_vector_type(4))) float  f32x4;   // MFMA C/D frag
typedef __attribute__((ext_vector_type(4))) unsigned short u16x4;
typedef _Float16 f16x2 __attribute__((ext_vector_type(2)));
typedef _Float16 f16x8 __attribute__((ext_vector_type(8)));
typedef unsigned short u16;

#define MFMA16B(A, B, C) __builtin_amdgcn_mfma_f32_16x16x32_bf16((A), (B), (C), 0, 0, 0)
#define MFMA16H(A, B, C) __builtin_amdgcn_mfma_f32_16x16x32_f16((A), (B), (C), 0, 0, 0)

static __device__ __forceinline__ u16 f2bf(float f) {
    union { float f; unsigned u; } v; v.f = f;
    unsigned r = (v.u + 0x7fffu + ((v.u >> 16) & 1u)) >> 16;   // RNE
    return (u16)r;
}

static __device__ __forceinline__ s16x8 pack_bf16x8(float4 a, float4 b) {
    s16x8 r;
    r[0] = (short)f2bf(a.x); r[1] = (short)f2bf(a.y); r[2] = (short)f2bf(a.z); r[3] = (short)f2bf(a.w);
    r[4] = (short)f2bf(b.x); r[5] = (short)f2bf(b.y); r[6] = (short)f2bf(b.z); r[7] = (short)f2bf(b.w);
    return r;
}

static __device__ __forceinline__ s16x8 pack_f16x8(float4 a, float4 b) {
    s16x8 r;
    r[0] = (short)__half_as_ushort(__float2half_rn(a.x));
    r[1] = (short)__half_as_ushort(__float2half_rn(a.y));
    r[2] = (short)__half_as_ushort(__float2half_rn(a.z));
    r[3] = (short)__half_as_ushort(__float2half_rn(a.w));
    r[4] = (short)__half_as_ushort(__float2half_rn(b.x));
    r[5] = (short)__half_as_ushort(__float2half_rn(b.y));
    r[6] = (short)__half_as_ushort(__float2half_rn(b.z));
    r[7] = (short)__half_as_ushort(__float2half_rn(b.w));
    return r;
}

static __device__ __forceinline__ unsigned pk2f16(float a, float b) {
    unsigned lo = __half_as_ushort(__float2half_rn(a));
    unsigned hi = __half_as_ushort(__float2half_rn(b));
    return lo | (hi << 16);
}

static __device__ __forceinline__ float hu2f(u16 v) {
    __half_raw hr; hr.x = v; return __half2float(__half(hr));
}

// 2-way f16 dot with f32 accumulate: v_dot2_f32_f16 when available.
static __device__ __forceinline__ float dot2(unsigned a, unsigned b, float c) {
#if __has_builtin(__builtin_amdgcn_fdot2)
    return __builtin_amdgcn_fdot2(__builtin_bit_cast(f16x2, a),
                                  __builtin_bit_cast(f16x2, b), c, false);
#else
    f16x2 av = __builtin_bit_cast(f16x2, a), bv = __builtin_bit_cast(f16x2, b);
    return fmaf((float)av[0], (float)bv[0], fmaf((float)av[1], (float)bv[1], c));
#endif
}

// fast sigmoid / tanh via v_exp + v_rcp (saturating, NaN-free at extremes)
static __device__ __forceinline__ float sigm(float x) {
    return __builtin_amdgcn_rcpf(1.f + __expf(-x));
}
static __device__ __forceinline__ float tanh_f(float x) {
    float e = __expf(-2.f * x);          // x->-inf: e=inf -> rcp=0 -> -1; x->+inf: e=0 -> +1
    return fmaf(2.f, __builtin_amdgcn_rcpf(1.f + e), -1.f);
}

// LDS-only workgroup barrier (no vmcnt drain).
static __device__ __forceinline__ void wg_barrier() {
    asm volatile("s_waitcnt lgkmcnt(0)\n\ts_barrier" ::: "memory");
}

// ---------------------------------------------------------------------------
// K1: x_gates[m=131072][512] (fp16) = x[m][300] @ W_ih^T + (b_ih + b_hh)
// v2: grid (4, 1024) so the 4 n-blocks sharing an x-tile are dispatch-adjacent
// (L2 reuse of x); bounds check hoisted out of chunks 0..8.
// ---------------------------------------------------------------------------
__global__ __launch_bounds__(256, 2)
void k1_gemm_xgates(const float* __restrict__ x, const float* __restrict__ W_ih,
                    const float* __restrict__ b_ih, const float* __restrict__ b_hh,
                    __half* __restrict__ xg) {
    const int n0 = blockIdx.x * 128;       // 4 blocks
    const int m0 = blockIdx.y * 128;       // 1024 blocks
    const int tid = threadIdx.x;
    const int wave = tid >> 6, lane = tid & 63;
    const int lanelo = lane & 15, quad = lane >> 4;
    const int mw = (wave & 1) * 64, nw = (wave >> 1) * 64;

    __shared__ __align__(16) u16 As[128 * 40];
    __shared__ __align__(16) u16 Bs[128 * 40];

    f32x4 acc[4][4];
#pragma unroll
    for (int i = 0; i < 4; ++i)
#pragma unroll
        for (int j = 0; j < 4; ++j) acc[i][j] = (f32x4)0.f;

    const int srow = tid >> 1;
    const int scol = (tid & 1) * 16;

    for (int kc = 0; kc < 10; ++kc) {
        const int k0 = kc * 32;
        const float* srcA = x + (size_t)(m0 + srow) * 300 + k0 + scol;
        const float* srcB = W_ih + (size_t)(n0 + srow) * 300 + k0 + scol;
        if (kc < 9) {                       // full chunk, no bounds checks
#pragma unroll
            for (int i = 0; i < 4; ++i) {
                const int col = scol + i * 4;
                float4 v = *(const float4*)(srcA + i * 4);
                u16x4 w; w.x = f2bf(v.x); w.y = f2bf(v.y); w.z = f2bf(v.z); w.w = f2bf(v.w);
                *(u16x4*)&As[srow * 40 + col] = w;
                float4 u = *(const float4*)(srcB + i * 4);
                u16x4 q; q.x = f2bf(u.x); q.y = f2bf(u.y); q.z = f2bf(u.z); q.w = f2bf(u.w);
                *(u16x4*)&Bs[srow * 40 + col] = q;
            }
        } else {                            // tail chunk (K 288..299, rest zero)
#pragma unroll
            for (int i = 0; i < 4; ++i) {
                const int col = scol + i * 4;
                float4 v = {0.f, 0.f, 0.f, 0.f}, u = {0.f, 0.f, 0.f, 0.f};
                if (k0 + col + 3 < 300) { v = *(const float4*)(srcA + i * 4);
                                          u = *(const float4*)(srcB + i * 4); }
                u16x4 w; w.x = f2bf(v.x); w.y = f2bf(v.y); w.z = f2bf(v.z); w.w = f2bf(v.w);
                *(u16x4*)&As[srow * 40 + col] = w;
                u16x4 q; q.x = f2bf(u.x); q.y = f2bf(u.y); q.z = f2bf(u.z); q.w = f2bf(u.w);
                *(u16x4*)&Bs[srow * 40 + col] = q;
            }
        }
        __syncthreads();

        s16x8 af[4], bf[4];
#pragma unroll
        for (int mt = 0; mt < 4; ++mt)
            af[mt] = *(const s16x8*)&As[(mw + mt * 16 + lanelo) * 40 + quad * 8];
#pragma unroll
        for (int nt = 0; nt < 4; ++nt)
            bf[nt] = *(const s16x8*)&Bs[(nw + nt * 16 + lanelo) * 40 + quad * 8];
#pragma unroll
        for (int mt = 0; mt < 4; ++mt)
#pragma unroll
            for (int nt = 0; nt < 4; ++nt)
                acc[mt][nt] = MFMA16B(af[mt], bf[nt], acc[mt][nt]);
        __syncthreads();
    }

#pragma unroll
    for (int nt = 0; nt < 4; ++nt) {
        const int n = n0 + nw + nt * 16 + lanelo;
        const float bs = b_ih[n] + b_hh[n];
#pragma unroll
        for (int mt = 0; mt < 4; ++mt) {
            const int mr = m0 + mw + mt * 16 + quad * 4;
#pragma unroll
            for (int r = 0; r < 4; ++r)
                xg[(size_t)(mr + r) * 512 + n] = __float2half(acc[mt][nt][r] + bs);
        }
    }
}

// ---------------------------------------------------------------------------
// K2 v4: LSTM recurrence via v_dot2_f32_f16 — no MFMA, no column waste.
// 128 WGs (one batch row each), 256 threads.
//   thread t: hj = t&127, gp = t>>7. gp=0 owns gate rows {i: hj, f: 128+hj};
//   gp=1 owns {g: 256+hj, o: 384+hj}. W_hh rows stationary in VGPRs as packed
//   f16 pairs (128 VGPRs/thread). h (f16-packed, 64 dwords) broadcast-read
//   from LDS each step; 128 dot2/thread = 256 VALU cycles/step.
//   gp=1 computes tanh(g), sigm(o), passes via LDS; gp=0 computes sigm(i),
//   sigm(f) in parallel, then the cell update. 2 LDS-only barriers/step.
//   xg staged 8 steps/chunk in LDS with register prefetch (vmcnt never
//   drained at barriers).
// ---------------------------------------------------------------------------
__global__ __launch_bounds__(256, 1)
void k2_lstm_rec(const __half* __restrict__ xg_all, const float* __restrict__ W_hh,
                 __half* __restrict__ h_seq) {
    const int bb = blockIdx.x;            // batch row 0..127
    const int tid = threadIdx.x;
    const int hj = tid & 127;
    const int gp = tid >> 7;              // 0: i,f   1: g,o

    __shared__ __align__(16) unsigned h_pk[64];       // 128 f16 (h_{t-1})
    __shared__ __align__(16) float2   ex[128];        // {tanh(g), sigm(o)}
    __shared__ __align__(16) u16 xg_lds[8][512];      // 8-step xg chunk (f16 bits)

    // --- stationary W_hh rows (f32 -> packed f16 pairs in VGPRs)
    unsigned w0[64], w1[64];
    {
        const float* r0p = W_hh + (size_t)(gp * 256 + hj) * 128;
        const float* r1p = W_hh + (size_t)(gp * 256 + 128 + hj) * 128;
#pragma unroll
        for (int k = 0; k < 64; ++k) {
            float2 a = ((const float2*)r0p)[k];
            float2 b = ((const float2*)r1p)[k];
            w0[k] = pk2f16(a.x, a.y);
            w1[k] = pk2f16(b.x, b.y);
        }
    }

    // --- xg chunk staging map: 256 threads x 32 B cover 8 steps x 512 u16
    const int pS = tid >> 5;              // step within chunk
    const int cS = (tid & 31) * 16;       // column
    const u16* xsrc = (const u16*)xg_all + (size_t)bb * 1024 * 512 + (size_t)pS * 512 + cS;

    // prime chunk 0
    s16x8 xr0 = *(const s16x8*)xsrc;
    s16x8 xr1 = *(const s16x8*)(xsrc + 8);
    if (tid < 64) h_pk[tid] = 0;
    float c = 0.f;
    *(s16x8*)&xg_lds[pS][cS] = xr0;
    *(s16x8*)&xg_lds[pS][cS + 8] = xr1;
    __syncthreads();

    __half* hout = h_seq + (size_t)bb * 1024 * 128 + hj;

    for (int t0 = 0; t0 < 1024; t0 += 8) {
        const bool have_next = (t0 + 8) < 1024;
        if (have_next) {                  // register prefetch; no barrier drains it
            const u16* s = xsrc + (size_t)(t0 + 8) * 512;
            xr0 = *(const s16x8*)s;
            xr1 = *(const s16x8*)(s + 8);
        }
        for (int p = 0; p < 8; ++p) {
            // xg preacts for my two gate rows (2-way bank aliasing: free)
            const float xa = hu2f(xg_lds[p][gp * 256 + hj]);
            const float xb = hu2f(xg_lds[p][gp * 256 + 128 + hj]);

            // 128 dot2: rows r0,r1 x K=128 (h broadcast from LDS)
            const uint4* hp4 = (const uint4*)h_pk;
            float a0 = 0.f, a1 = 0.f, b0 = 0.f, b1 = 0.f;
#pragma unroll
            for (int j = 0; j < 16; ++j) {
                const uint4 hv = hp4[j];
                const int k = j * 4;
                a0 = dot2(w0[k + 0], hv.x, a0); b0 = dot2(w1[k + 0], hv.x, b0);
                a1 = dot2(w0[k + 1], hv.y, a1); b1 = dot2(w1[k + 1], hv.y, b1);
                a0 = dot2(w0[k + 2], hv.z, a0); b0 = dot2(w1[k + 2], hv.z, b0);
                a1 = dot2(w0[k + 3], hv.w, a1); b1 = dot2(w1[k + 3], hv.w, b1);
            }
            const float g0 = a0 + a1 + xa;    // row r0 preact (i or g)
            const float g1 = b0 + b1 + xb;    // row r1 preact (f or o)

            float ia = 0.f, fa = 0.f;
            if (gp) {                          // g,o half: activate + publish
                ex[hj] = make_float2(tanh_f(g0), sigm(g1));
            } else {                           // i,f half: activate in parallel
                ia = sigm(g0); fa = sigm(g1);
            }
            wg_barrier();                      // B1: ex visible
            if (!gp) {
                const float2 go = ex[hj];
                c = fmaf(fa, c, ia * go.x);
                const float h = go.y * tanh_f(c);
                const __half hh = __float2half(h);
                ((u16*)h_pk)[hj] = (u16)__half_as_ushort(hh);
                hout[(size_t)(t0 + p) * 128] = hh;   // fire-and-forget store
            }
            wg_barrier();                      // B2: new h visible
        }
        if (have_next) {   // xr -> LDS; compiler waits vmcnt for xr here only
            *(s16x8*)&xg_lds[pS][cS] = xr0;
            *(s16x8*)&xg_lds[pS][cS + 8] = xr1;
            wg_barrier();
        }
    }
}

// ---------------------------------------------------------------------------
// K3: y[m=131072][64] = h_seq(f16)[m][128] @ W1^T + b1   (f16 MFMA now)
// ---------------------------------------------------------------------------
__global__ __launch_bounds__(256, 2)
void k3_gemm_out(const u16* __restrict__ hseq, const float* __restrict__ W1,
                 const float* __restrict__ b1, float* __restrict__ y) {
    const int m0 = blockIdx.x * 128;
    const int tid = threadIdx.x;
    const int wave = tid >> 6, lane = tid & 63;
    const int lanelo = lane & 15, quad = lane >> 4;

    __shared__ __align__(16) u16 Ah[128 * 136];
    __shared__ __align__(16) u16 Bw[64 * 136];
    __shared__ float b1s[64];

    {
        const int row = tid >> 1, cg = (tid & 1) * 64;
        const u16* src = hseq + (size_t)(m0 + row) * 128 + cg;
#pragma unroll
        for (int i = 0; i < 8; ++i)
            *(s16x8*)&Ah[row * 136 + cg + i * 8] = *(const s16x8*)(src + i * 8);
    }
    {
        const int row = tid >> 2, cg = (tid & 3) * 32;
        const float* src = W1 + (size_t)row * 128 + cg;
#pragma unroll
        for (int i = 0; i < 4; ++i) {
            float4 v0 = *(const float4*)(src + i * 8);
            float4 v1 = *(const float4*)(src + i * 8 + 4);
            *(s16x8*)&Bw[row * 136 + cg + i * 8] = pack_f16x8(v0, v1);
        }
    }
    if (tid < 64) b1s[tid] = b1[tid];
    __syncthreads();

    f16x8 af[2][4], bf[4][4];
#pragma unroll
    for (int mt = 0; mt < 2; ++mt)
#pragma unroll
        for (int kt = 0; kt < 4; ++kt)
            af[mt][kt] = __builtin_bit_cast(f16x8,
                *(const s16x8*)&Ah[(wave * 32 + mt * 16 + lanelo) * 136 + kt * 32 + quad * 8]);
#pragma unroll
    for (int nt = 0; nt < 4; ++nt)
#pragma unroll
        for (int kt = 0; kt < 4; ++kt)
            bf[nt][kt] = __builtin_bit_cast(f16x8,
                *(const s16x8*)&Bw[(nt * 16 + lanelo) * 136 + kt * 32 + quad * 8]);

    f32x4 acc[2][4];
#pragma unroll
    for (int mt = 0; mt < 2; ++mt)
#pragma unroll
        for (int nt = 0; nt < 4; ++nt) acc[mt][nt] = (f32x4)0.f;
#pragma unroll
    for (int kt = 0; kt < 4; ++kt)
#pragma unroll
        for (int mt = 0; mt < 2; ++mt)
#pragma unroll
            for (int nt = 0; nt < 4; ++nt)
                acc[mt][nt] = MFMA16H(af[mt][kt], bf[nt][kt], acc[mt][nt]);

#pragma unroll
    for (int mt = 0; mt < 2; ++mt)
#pragma unroll
        for (int nt = 0; nt < 4; ++nt) {
            const int n = nt * 16 + lanelo;
            const float bs = b1s[n];
            const int mr = m0 + wave * 32 + mt * 16 + quad * 4;
#pragma unroll
            for (int r = 0; r < 4; ++r)
                y[(size_t)(mr + r) * 64 + n] = acc[mt][nt][r] + bs;
        }
}

// ---------------------------------------------------------------------------
extern "C" void kernel_launch(void* const* d_in, const int* in_sizes, int n_in,
                              void* d_out, int out_size, void* d_ws, size_t ws_size,
                              hipStream_t stream) {
    const float* x    = (const float*)d_in[0];
    const float* W_ih = (const float*)d_in[1];
    const float* W_hh = (const float*)d_in[2];
    const float* b_ih = (const float*)d_in[3];
    const float* b_hh = (const float*)d_in[4];
    const float* W1   = (const float*)d_in[5];
    const float* b1   = (const float*)d_in[6];
    float* y = (float*)d_out;

    const size_t XG_BYTES = (size_t)131072 * 512 * 2;   // x_gates fp16: 134 MB
    const size_t HS_BYTES = (size_t)131072 * 128 * 2;   // h_seq  fp16:  33.5 MB
    if (ws_size < XG_BYTES + HS_BYTES) return;

    __half* xg   = (__half*)d_ws;
    __half* hseq = (__half*)((char*)d_ws + XG_BYTES);

    k1_gemm_xgates<<<dim3(4, 1024), 256, 0, stream>>>(x, W_ih, b_ih, b_hh, xg);
    k2_lstm_rec<<<128, 256, 0, stream>>>(xg, W_hh, hseq);
    k3_gemm_out<<<1024, 256, 0, stream>>>((const u16*)hseq, W1, b1, y);
}